// Round 1
// 204.043 us; speedup vs baseline: 1.0367x; 1.0367x over previous
//
#include <hip/hip_runtime.h>
#include <hip/hip_bf16.h>

#define B_ 4
#define C_ 512
#define T_ 1024
#define SCALE_ 0.125f
#define EPS_ 1e-5f

typedef unsigned short u16;
typedef __attribute__((ext_vector_type(8))) unsigned short u16x8;
typedef __attribute__((ext_vector_type(4))) unsigned short u16x4;
typedef __attribute__((ext_vector_type(8))) short s16x8;
typedef __attribute__((ext_vector_type(4))) float f32x4;

// ws byte offsets (ws is 256 MiB)
#define QT_OFF    (0x0ull)         // bf16 Qt[B][T][C]   4 MB (Q pre-scaled by 1/8)
#define KT_OFF    (0x400000ull)    // bf16 Kt[B][T][C]   4 MB
#define V_OFF     (0x800000ull)    // bf16 V [B][C][T]   4 MB
#define XT_OFF    (0xC00000ull)    // bf16 Xt[B][T][C]   4 MB
#define O_OFF     (0x1000000ull)   // bf16 O[B][8][T][64] 4 MB (normalized, pre-affine)
#define AB_OFF    (0x1410000ull)   // fp32 ab[B][8][2]
#define VSUM_OFF  (0x1420000ull)   // fp32 vsum[B][8][64]
#define BIAS2_OFF (0x1430000ull)   // fp32 bias2[B][8][512]  (64 KB, ends 0x1440000)
#define LSUM_OFF  (0x1440000ull)   // fp32 lsum [B*8][1024]  128 KB
#define L2SUM_OFF (0x1460000ull)   // fp32 l2sum[B*8][1024]  128 KB

static __device__ __forceinline__ u16 f2bf(float f) {
  unsigned u = __float_as_uint(f);
  unsigned r = (u + 0x7fff + ((u >> 16) & 1)) >> 16;  // RNE
  return (u16)r;
}
static __device__ __forceinline__ float b2f(u16 x) {
  return __uint_as_float(((unsigned)x) << 16);
}
static __device__ __forceinline__ f32x4 mfma16(s16x8 a, s16x8 b, f32x4 c) {
  return __builtin_amdgcn_mfma_f32_16x16x32_bf16(a, b, c, 0, 0, 0);
}

// ---------------- transpose x -> Xt[b][t][c] bf16 ----------------
__global__ __launch_bounds__(256) void transpose_x(const float* __restrict__ x,
                                                   u16* __restrict__ xt) {
  const int b = blockIdx.z;
  const int t0 = blockIdx.x << 6;
  const int c0 = blockIdx.y << 6;
  const float* __restrict__ X = x + (size_t)b * (C_ * (size_t)T_);
  u16* __restrict__ Xt = xt + (size_t)b * (T_ * (size_t)C_);
  __shared__ float Ts[64][65];
  const int tid = threadIdx.x;
#pragma unroll
  for (int i = 0; i < 4; ++i) {
    const int e = tid + (i << 8);
    const int r = e >> 4, c4 = e & 15;
    const float4 v = *(const float4*)(X + (size_t)(c0 + r) * T_ + t0 + (c4 << 2));
    Ts[r][(c4 << 2) + 0] = v.x; Ts[r][(c4 << 2) + 1] = v.y;
    Ts[r][(c4 << 2) + 2] = v.z; Ts[r][(c4 << 2) + 3] = v.w;
  }
  __syncthreads();
#pragma unroll
  for (int i = 0; i < 2; ++i) {
    const int e = tid + (i << 8);
    const int tt = e >> 3, c8 = e & 7;
    u16x8 o;
#pragma unroll
    for (int j = 0; j < 8; ++j) o[j] = f2bf(Ts[(c8 << 3) + j][tt]);
    *(u16x8*)(Xt + (size_t)(t0 + tt) * C_ + c0 + (c8 << 3)) = o;
  }
}

// ------- Qt/Kt = Xt @ W^T -> [t][o] bf16 (Q scaled by 1/8), 64x64 tiles -----
__global__ __launch_bounds__(256) void gemm_qkt(const u16* __restrict__ xt,
                                                const float* __restrict__ wq,
                                                const float* __restrict__ wk,
                                                u16* __restrict__ qto,
                                                u16* __restrict__ kto) {
  const int which = blockIdx.z >> 2;
  const int b = blockIdx.z & 3;
  const float* __restrict__ W = which ? wk : wq;
  u16* __restrict__ Y = (which ? kto : qto) + (size_t)b * (T_ * (size_t)C_);
  const u16* __restrict__ A = xt + (size_t)b * (T_ * (size_t)C_);
  const float sc = which ? 1.0f : SCALE_;
  const int m0 = blockIdx.x << 6;  // t
  const int n0 = blockIdx.y << 6;  // o
  __shared__ u16 As[64][72];
  __shared__ u16 Bs[64][72];
  const int tid = threadIdx.x;
  const int w = tid >> 6, lane = tid & 63, lr = lane & 15, lq = lane >> 4;
  const int mw = (w >> 1) << 5, nw = (w & 1) << 5;
  f32x4 acc[2][2] = {};
  for (int k0 = 0; k0 < C_; k0 += 64) {
#pragma unroll
    for (int it = 0; it < 2; ++it) {
      const int e = tid + (it << 8);
      const int r = e >> 3, c8 = e & 7;
      *(u16x8*)&As[r][c8 << 3] =
          *(const u16x8*)(A + (size_t)(m0 + r) * C_ + k0 + (c8 << 3));
      const float* wr = W + (size_t)(n0 + r) * C_ + k0 + (c8 << 3);
      const float4 f0 = *(const float4*)wr;
      const float4 f1 = *(const float4*)(wr + 4);
      u16x8 o;
      o[0] = f2bf(f0.x); o[1] = f2bf(f0.y); o[2] = f2bf(f0.z); o[3] = f2bf(f0.w);
      o[4] = f2bf(f1.x); o[5] = f2bf(f1.y); o[6] = f2bf(f1.z); o[7] = f2bf(f1.w);
      *(u16x8*)&Bs[r][c8 << 3] = o;
    }
    __syncthreads();
#pragma unroll
    for (int kf = 0; kf < 2; ++kf) {
      const int ko = (kf << 5) + (lq << 3);
      s16x8 a[2], bb[2];
#pragma unroll
      for (int i = 0; i < 2; ++i) a[i] = *(const s16x8*)&As[mw + (i << 4) + lr][ko];
#pragma unroll
      for (int j = 0; j < 2; ++j) bb[j] = *(const s16x8*)&Bs[nw + (j << 4) + lr][ko];
#pragma unroll
      for (int i = 0; i < 2; ++i)
#pragma unroll
        for (int j = 0; j < 2; ++j) acc[i][j] = mfma16(a[i], bb[j], acc[i][j]);
    }
    __syncthreads();
  }
#pragma unroll
  for (int i = 0; i < 2; ++i) {
    const int row = mw + (i << 4) + (lq << 2);
#pragma unroll
    for (int j = 0; j < 2; ++j) {
      const int col = nw + (j << 4) + lr;
#pragma unroll
      for (int r = 0; r < 4; ++r)
        Y[(size_t)(m0 + row + r) * C_ + n0 + col] = f2bf(acc[i][j][r] * sc);
    }
  }
}

// ---------------- V = Wv @ X  -> [o][t] bf16, 64x64 tiles ----------------
__global__ __launch_bounds__(256) void gemm_v(const u16* __restrict__ xt,
                                              const float* __restrict__ wv,
                                              u16* __restrict__ vout) {
  const int b = blockIdx.z;
  const int n0 = blockIdx.x << 6;  // t
  const int m0 = blockIdx.y << 6;  // o
  const u16* __restrict__ Bg = xt + (size_t)b * (T_ * (size_t)C_);
  u16* __restrict__ Y = vout + (size_t)b * (C_ * (size_t)T_);
  __shared__ u16 As[64][72];
  __shared__ u16 Bs[64][72];
  const int tid = threadIdx.x;
  const int w = tid >> 6, lane = tid & 63, lr = lane & 15, lq = lane >> 4;
  const int mw = (w >> 1) << 5, nw = (w & 1) << 5;
  f32x4 acc[2][2] = {};
  for (int k0 = 0; k0 < C_; k0 += 64) {
#pragma unroll
    for (int it = 0; it < 2; ++it) {
      const int e = tid + (it << 8);
      const int r = e >> 3, c8 = e & 7;
      const float* wr = wv + (size_t)(m0 + r) * C_ + k0 + (c8 << 3);
      const float4 f0 = *(const float4*)wr;
      const float4 f1 = *(const float4*)(wr + 4);
      u16x8 o;
      o[0] = f2bf(f0.x); o[1] = f2bf(f0.y); o[2] = f2bf(f0.z); o[3] = f2bf(f0.w);
      o[4] = f2bf(f1.x); o[5] = f2bf(f1.y); o[6] = f2bf(f1.z); o[7] = f2bf(f1.w);
      *(u16x8*)&As[r][c8 << 3] = o;
      *(u16x8*)&Bs[r][c8 << 3] =
          *(const u16x8*)(Bg + (size_t)(n0 + r) * C_ + k0 + (c8 << 3));
    }
    __syncthreads();
#pragma unroll
    for (int kf = 0; kf < 2; ++kf) {
      const int ko = (kf << 5) + (lq << 3);
      s16x8 a[2], bb[2];
#pragma unroll
      for (int i = 0; i < 2; ++i) a[i] = *(const s16x8*)&As[mw + (i << 4) + lr][ko];
#pragma unroll
      for (int j = 0; j < 2; ++j) bb[j] = *(const s16x8*)&Bs[nw + (j << 4) + lr][ko];
#pragma unroll
      for (int i = 0; i < 2; ++i)
#pragma unroll
        for (int j = 0; j < 2; ++j) acc[i][j] = mfma16(a[i], bb[j], acc[i][j]);
    }
    __syncthreads();
  }
#pragma unroll
  for (int i = 0; i < 2; ++i) {
    const int row = mw + (i << 4) + (lq << 2);
#pragma unroll
    for (int j = 0; j < 2; ++j) {
      const int col = nw + (j << 4) + lr;
#pragma unroll
      for (int r = 0; r < 4; ++r)
        Y[(size_t)(m0 + row + r) * T_ + n0 + col] = f2bf(acc[i][j][r]);
    }
  }
}

// ---------------- vsum[b][g][d] = sum_t V ----------------
__global__ __launch_bounds__(256) void vsum_k(const u16* __restrict__ v,
                                              float* __restrict__ vsum) {
  const int bg = blockIdx.x;  // b*8+g
  const int tid = threadIdx.x;
  const int d = tid >> 2, part = tid & 3;
  const u16* __restrict__ Vr =
      v + ((size_t)(bg >> 3) * C_ + ((bg & 7) << 6) + d) * T_ + (part << 8);
  float s = 0.f;
  for (int t = 0; t < 256; t += 8) {
    const u16x8 x = *(const u16x8*)(Vr + t);
#pragma unroll
    for (int j = 0; j < 8; ++j) s += b2f(x[j]);
  }
  s += __shfl_down(s, 2, 64);
  s += __shfl_down(s, 1, 64);
  if (part == 0) vsum[(bg << 6) + d] = s;
}

// ---- FUSED attention: S^T=K·Q^T (permuted K rows), head-mix, exp -> P in
// LDS -> PV, all in one kernel. 512 thr / 8 waves, q-tile 16, grid 256.
// Per 256-t chunk: wave w computes QK+mix+exp for t-window w*32 (all 8 g),
// writes P[8g][16q][256t] to LDS; barrier; wave w then does PV for g=w over
// the whole chunk (acc[4] f32x4 = O[g][16q][64d] partial, all t covered by
// the wave itself -> no cross-wave O reduce). l,l2 finished in-block; O
// stored normalized (pre-affine). Kills the 64MB P write + 64MB P re-read.
// XCD swizzle: xcd=id&7 -> b=xcd>>1, so each XCD's L2 holds one b's K+V (2MB).
__global__ __launch_bounds__(512, 2) void attn_fused(
    const u16* __restrict__ Qt, const u16* __restrict__ Kt,
    const u16* __restrict__ v, const float* __restrict__ wh,
    u16* __restrict__ O, float* __restrict__ lsum_g,
    float* __restrict__ l2sum_g) {
  const int id = blockIdx.x;
  const int xcd = id & 7;
  const int b = xcd >> 1;
  const int qb = ((xcd & 1) << 5) | (id >> 3);
  const int q0 = qb << 4;
  const int tid = threadIdx.x;
  const int w = tid >> 6, lane = tid & 63;
  const int lr = lane & 15, quad = lane >> 4;

  __shared__ __align__(16) u16 Qs[16][522];
  __shared__ __align__(16) u16 Plds[8][16][264];  // [g][q][t(chunk)] pad->2-way
  __shared__ float lbuf[8][8][16];                // [wave][g][q]
  __shared__ float l2buf[8][8][16];
  __shared__ float linvS[8][16];

  {  // stage Q tile (16 x 512)
    const u16* Qb = Qt + ((size_t)b * T_ + q0) * C_;
    for (int i = tid; i < 1024; i += 512) {
      const int r = i >> 6, c8 = i & 63;
      *(u16x8*)&Qs[r][c8 << 3] = *(const u16x8*)(Qb + (size_t)r * C_ + (c8 << 3));
    }
  }

  const int tp = ((lr >> 2) << 3) + (lr & 3);  // permuted K row (R8-validated)
  const u16* __restrict__ Qrow = &Qs[lr][quad << 3];
  const int g = w;  // PV head owned by this wave
  const u16* __restrict__ Vg = v + ((size_t)b * C_ + (g << 6)) * (size_t)T_;

  float lacc[8] = {}, l2acc[8] = {};
  f32x4 acc[4] = {};

  __syncthreads();

  for (int c = 0; c < 4; ++c) {
    // ---- QK + mix + exp for this wave's 32-t window ----
    const int tbase = (c << 8) + (w << 5);
    const u16* __restrict__ K0 =
        Kt + ((size_t)b * T_ + tbase + tp) * C_ + (quad << 3);
    const u16* __restrict__ K1 = K0 + 4 * C_;
    f32x4 m[8][2] = {};
#pragma unroll 2
    for (int h = 0; h < 8; ++h) {
      f32x4 a0 = {0.f, 0.f, 0.f, 0.f}, a1 = {0.f, 0.f, 0.f, 0.f};
#pragma unroll
      for (int kf = 0; kf < 2; ++kf) {
        const int co = (h << 6) + (kf << 5);
        const s16x8 qf = *(const s16x8*)(Qrow + co);
        const s16x8 k0 = *(const s16x8*)(K0 + co);
        const s16x8 k1 = *(const s16x8*)(K1 + co);
        a0 = mfma16(k0, qf, a0);
        a1 = mfma16(k1, qf, a1);
      }
#pragma unroll
      for (int gg = 0; gg < 8; ++gg) {
        const float wgh = wh[(gg << 3) + h];  // uniform -> SGPR
        m[gg][0] += a0 * wgh;
        m[gg][1] += a1 * wgh;
      }
    }
    // lane's t slots: m[gg][0] -> w*32+quad*8+{0..3}, m[gg][1] -> +{4..7}; q=lr
#pragma unroll
    for (int gg = 0; gg < 8; ++gg) {
      f32x4 e0, e1;
#pragma unroll
      for (int k = 0; k < 4; ++k) {
        e0[k] = __expf(m[gg][0][k]);
        e1[k] = __expf(m[gg][1][k]);
      }
      u16x8 o;
#pragma unroll
      for (int k = 0; k < 4; ++k) {
        o[k] = f2bf(e0[k]);
        o[k + 4] = f2bf(e1[k]);
      }
      *(u16x8*)&Plds[gg][lr][(w << 5) + (quad << 3)] = o;
      lacc[gg] += e0[0] + e0[1] + e0[2] + e0[3] + e1[0] + e1[1] + e1[2] + e1[3];
      l2acc[gg] += e0[0] * e0[0] + e0[1] * e0[1] + e0[2] * e0[2] + e0[3] * e0[3] +
                   e1[0] * e1[0] + e1[1] * e1[1] + e1[2] * e1[2] + e1[3] * e1[3];
    }
    __syncthreads();  // P ready
    // ---- PV: this wave's g over the whole 256-t chunk ----
#pragma unroll
    for (int tw = 0; tw < 8; ++tw) {
      const int t0 = (c << 8) + (tw << 5);
      const s16x8 pa = *(const s16x8*)&Plds[g][lr][(tw << 5) + (quad << 3)];
#pragma unroll
      for (int dj = 0; dj < 4; ++dj) {
        const s16x8 vb =
            *(const s16x8*)(Vg + (size_t)((dj << 4) + lr) * T_ + t0 + (quad << 3));
        acc[dj] = mfma16(pa, vb, acc[dj]);
      }
    }
    __syncthreads();  // P consumed, safe to overwrite next chunk
  }

  // ---- finish l/l2: quad-reduce, cross-wave reduce, linv + global stats ----
#pragma unroll
  for (int gg = 0; gg < 8; ++gg) {
    float l = lacc[gg];
    l += __shfl_xor(l, 16, 64);
    l += __shfl_xor(l, 32, 64);
    float l2 = l2acc[gg];
    l2 += __shfl_xor(l2, 16, 64);
    l2 += __shfl_xor(l2, 32, 64);
    if (quad == 0) {
      lbuf[w][gg][lr] = l;
      l2buf[w][gg][lr] = l2;
    }
  }
  __syncthreads();
  const int bg = (b << 3) + g;
  if (lane < 16) {
    float l = 0.f, l2 = 0.f;
#pragma unroll
    for (int w2 = 0; w2 < 8; ++w2) {
      l += lbuf[w2][g][lr];
      l2 += l2buf[w2][g][lr];
    }
    linvS[g][lr] = 1.f / l;
    lsum_g[((size_t)bg << 10) + q0 + lr] = l;
    l2sum_g[((size_t)bg << 10) + q0 + lr] = l2;
  }
  __syncthreads();
  float li[4];
#pragma unroll
  for (int r = 0; r < 4; ++r) li[r] = linvS[g][(quad << 2) + r];
#pragma unroll
  for (int dj = 0; dj < 4; ++dj) {
    const int d = (dj << 4) + lr;
#pragma unroll
    for (int r = 0; r < 4; ++r) {
      const int q = (quad << 2) + r;
      O[(((size_t)bg << 10) + q0 + q) * 64 + d] = f2bf(acc[dj][r] * li[r]);
    }
  }
}

// ---- reduce per-q l/l2 -> alpha/beta' per (b,g) -> ab ----
__global__ __launch_bounds__(256) void reduce_l(const float* __restrict__ lsum,
                                                const float* __restrict__ l2sum,
                                                const float* __restrict__ gamma,
                                                const float* __restrict__ beta,
                                                float* __restrict__ ab) {
  const int bg = blockIdx.x;
  const int g = bg & 7;
  const int tid = threadIdx.x;
  const f32x4 l = *(const f32x4*)(lsum + ((size_t)bg << 10) + (tid << 2));
  const f32x4 l2 = *(const f32x4*)(l2sum + ((size_t)bg << 10) + (tid << 2));
  float ssq = 0.f;
#pragma unroll
  for (int k = 0; k < 4; ++k) ssq += l2[k] / (l[k] * l[k]);
#pragma unroll
  for (int off = 32; off; off >>= 1) ssq += __shfl_xor(ssq, off, 64);
  __shared__ float red[4];
  if ((tid & 63) == 0) red[tid >> 6] = ssq;
  __syncthreads();
  if (tid == 0) {
    const float s = red[0] + red[1] + red[2] + red[3];
    const float mean = 0.0009765625f;
    const float var = s * (1.f / 1048576.f) - mean * mean;
    const float al = gamma[g] * rsqrtf(var + EPS_);
    ab[bg * 2] = al;
    ab[bg * 2 + 1] = beta[g] - al * mean;
  }
}

// -------- bias2[b][g][o] = bp[o] + bt2[b,g] * sum_d vsum[b,g,d]*wsum[o][d]
__global__ __launch_bounds__(256) void bias2_k(const float* __restrict__ wp,
                                               const float* __restrict__ bp,
                                               const float* __restrict__ ab,
                                               const float* __restrict__ vsum,
                                               float* __restrict__ bias2) {
  const int idx = (blockIdx.x << 8) + threadIdx.x;  // 16384 = B*8*512
  const int b = idx >> 12, g = (idx >> 9) & 7, o = idx & 511;
  const float bt2 = ab[(((b << 3) + g) << 1) + 1];
  const float* wr = wp + (size_t)o * C_;
  const float* vs = vsum + (((b << 3) + g) << 6);
  float acc = 0.f;
#pragma unroll
  for (int d = 0; d < 64; d += 4) {
    const float4 vv4 = *(const float4*)(vs + d);
    float4 ws4 = {0.f, 0.f, 0.f, 0.f};
#pragma unroll
    for (int j = 0; j < 8; ++j) {
      const float4 wv4 = *(const float4*)(wr + (j << 6) + d);
      ws4.x += wv4.x; ws4.y += wv4.y; ws4.z += wv4.z; ws4.w += wv4.w;
    }
    acc += ws4.x * vv4.x + ws4.y * vv4.y + ws4.z * vv4.z + ws4.w * vv4.w;
  }
  bias2[(((b << 3) + g) << 9) + o] = bp[o] + bt2 * acc;
}

// ------- y = al[b,g(t)]*(Mnorm @ Wp^T) + bias2[b][g(t)][o], 64x64 tiles ----
__global__ __launch_bounds__(256) void gemm_proj(const u16* __restrict__ O,
                                                 const float* __restrict__ wp,
                                                 const float* __restrict__ ab,
                                                 const float* __restrict__ bias2,
                                                 float* __restrict__ y) {
  const int b = blockIdx.z;
  const int m0 = blockIdx.y << 6;  // o
  const int n0 = blockIdx.x << 6;  // t
  const int gidx = blockIdx.x >> 1;
  const u16* __restrict__ Ob = O + (size_t)b * (8 * T_ * 64);
  __shared__ u16 As[64][72];
  __shared__ u16 Bs[64][72];
  const int tid = threadIdx.x;
  const int w = tid >> 6, lane = tid & 63, lr = lane & 15, lq = lane >> 4;
  const int mw = (w >> 1) << 5, nw = (w & 1) << 5;
  f32x4 acc[2][2] = {};
  for (int k0 = 0; k0 < C_; k0 += 64) {
#pragma unroll
    for (int it = 0; it < 2; ++it) {
      const int e = tid + (it << 8);
      const int r = e >> 3, c8 = e & 7;
      const float* wr = wp + (size_t)(m0 + r) * C_ + k0 + (c8 << 3);
      const float4 f0 = *(const float4*)wr;
      const float4 f1 = *(const float4*)(wr + 4);
      u16x8 o;
      o[0] = f2bf(f0.x); o[1] = f2bf(f0.y); o[2] = f2bf(f0.z); o[3] = f2bf(f0.w);
      o[4] = f2bf(f1.x); o[5] = f2bf(f1.y); o[6] = f2bf(f1.z); o[7] = f2bf(f1.w);
      *(u16x8*)&As[r][c8 << 3] = o;
      const int t = n0 + r;
      const int c = k0 + (c8 << 3);
      *(u16x8*)&Bs[r][c8 << 3] =
          *(const u16x8*)(Ob + (size_t)(t >> 7) * (T_ * 64) +
                          (size_t)(((t & 127) << 3) + (c >> 6)) * 64 + (c & 63));
    }
    __syncthreads();
#pragma unroll
    for (int kf = 0; kf < 2; ++kf) {
      const int ko = (kf << 5) + (lq << 3);
      s16x8 a[2], bb[2];
#pragma unroll
      for (int i = 0; i < 2; ++i) a[i] = *(const s16x8*)&As[mw + (i << 4) + lr][ko];
#pragma unroll
      for (int j = 0; j < 2; ++j) bb[j] = *(const s16x8*)&Bs[nw + (j << 4) + lr][ko];
#pragma unroll
      for (int i = 0; i < 2; ++i)
#pragma unroll
        for (int j = 0; j < 2; ++j) acc[i][j] = mfma16(a[i], bb[j], acc[i][j]);
    }
    __syncthreads();
  }
  const float al = ab[(((b << 3) + gidx) << 1)];
  const float* __restrict__ b2 = bias2 + (((b << 3) + gidx) << 9);
#pragma unroll
  for (int i = 0; i < 2; ++i) {
    const int row = mw + (i << 4) + (lq << 2);
#pragma unroll
    for (int j = 0; j < 2; ++j) {
      const int col = nw + (j << 4) + lr;
#pragma unroll
      for (int r = 0; r < 4; ++r)
        y[(size_t)b * (C_ * (size_t)T_) + (size_t)(m0 + row + r) * T_ + n0 + col] =
            acc[i][j][r] * al + b2[m0 + row + r];
    }
  }
}

extern "C" void kernel_launch(void* const* d_in, const int* in_sizes, int n_in,
                              void* d_out, int out_size, void* d_ws,
                              size_t ws_size, hipStream_t stream) {
  const float* x = (const float*)d_in[0];
  const float* wq = (const float*)d_in[1];
  const float* wk = (const float*)d_in[2];
  const float* wv = (const float*)d_in[3];
  const float* wh = (const float*)d_in[4];
  const float* gm = (const float*)d_in[5];
  const float* bt = (const float*)d_in[6];
  const float* wp = (const float*)d_in[7];
  const float* bp = (const float*)d_in[8];
  float* y = (float*)d_out;
  char* wsb = (char*)d_ws;

  u16* Qt = (u16*)(wsb + QT_OFF);
  u16* Kt = (u16*)(wsb + KT_OFF);
  u16* V = (u16*)(wsb + V_OFF);
  u16* Xt = (u16*)(wsb + XT_OFF);
  u16* Og = (u16*)(wsb + O_OFF);
  float* ab = (float*)(wsb + AB_OFF);
  float* vsum = (float*)(wsb + VSUM_OFF);
  float* bias2 = (float*)(wsb + BIAS2_OFF);
  float* lsum = (float*)(wsb + LSUM_OFF);
  float* l2sum = (float*)(wsb + L2SUM_OFF);

  transpose_x<<<dim3(16, 8, 4), 256, 0, stream>>>(x, Xt);
  gemm_qkt<<<dim3(16, 8, 8), 256, 0, stream>>>(Xt, wq, wk, Qt, Kt);
  gemm_v<<<dim3(16, 8, 4), 256, 0, stream>>>(Xt, wv, V);
  vsum_k<<<dim3(32), 256, 0, stream>>>(V, vsum);
  attn_fused<<<dim3(256), 512, 0, stream>>>(Qt, Kt, V, wh, Og, lsum, l2sum);
  reduce_l<<<dim3(32), 256, 0, stream>>>(lsum, l2sum, gm, bt, ab);
  bias2_k<<<dim3(64), 256, 0, stream>>>(wp, bp, ab, vsum, bias2);
  gemm_proj<<<dim3(16, 8, 4), 256, 0, stream>>>(Og, wp, ab, bias2, y);
}